// Round 7
// baseline (412.502 us; speedup 1.0000x reference)
//
#include <hip/hip_runtime.h>

// ---------- types ----------
typedef __attribute__((ext_vector_type(8))) short bf16x8;   // 8 bf16 (4 VGPRs)
typedef __attribute__((ext_vector_type(4))) float f32x4;

__device__ __forceinline__ unsigned short f2bf(float f) {
    unsigned int u = __float_as_uint(f);
    unsigned int r = (u + 0x7fffu + ((u >> 16) & 1u)) >> 16;   // RNE
    return (unsigned short)r;
}

// x: (8,1024,64,64) f32; W: (1024,1049) f32; b: (1024,); out: (8,1024,64,64) f32
// M = 32768, K = 1049 -> pad 1088 (17 K-tiles of 64), N = 1024
#define KPAD 1088
#define NT   17

// ---------- kernel: W (1024,1049) f32 -> Wb[n][k] bf16, k padded to 1088 ----------
__global__ void kWb_conv(const float* __restrict__ W, unsigned short* __restrict__ Wb)
{
    const int o = blockIdx.x;
    for (int k = threadIdx.x; k < KPAD; k += 256) {
        float v = (k < 1049) ? W[(size_t)o * 1049 + k] : 0.f;
        Wb[(size_t)o * KPAD + k] = f2bf(v);
    }
}

// ---------- kernel: transpose+convert x -> xT[m][k] bf16 (k<1024 region) ----------
__global__ __launch_bounds__(256) void kT_conv(const float* __restrict__ x,
                                               unsigned short* __restrict__ xT)
{
    __shared__ unsigned short tile[64][128];
    const int bid = blockIdx.x;          // 4096 = 512 mtiles * 8 ctiles
    const int mst = bid >> 3;
    const int ct  = bid & 7;
    const int m0  = mst * 64;
    const int b   = m0 >> 12, ms0 = m0 & 4095;
    const int t   = threadIdx.x;
    const int msq = (t & 15) * 4;
    const int cg  = t >> 4;
    const int c0  = ct * 128 + cg * 8;

    const float* src = x + ((size_t)b * 1024 + c0) * 4096 + ms0 + msq;
    float4 v[8];
    #pragma unroll
    for (int j = 0; j < 8; ++j)
        v[j] = *(const float4*)(src + (size_t)j * 4096);

    #pragma unroll
    for (int p = 0; p < 4; ++p) {
        unsigned int w[4];
        #pragma unroll
        for (int q = 0; q < 4; ++q) {
            float lo = ((const float*)&v[2 * q])[p];
            float hi = ((const float*)&v[2 * q + 1])[p];
            w[q] = (unsigned int)f2bf(lo) | ((unsigned int)f2bf(hi) << 16);
        }
        const int row = msq + p;
        const int pch = cg ^ ((row >> 2) & 15);
        *(uint4*)&tile[row][pch * 8] = make_uint4(w[0], w[1], w[2], w[3]);
    }
    __syncthreads();

    #pragma unroll
    for (int q = 0; q < 4; ++q) {
        const int flat = q * 256 + t;
        const int row  = flat >> 4, ch = flat & 15;
        const int pch  = ch ^ ((row >> 2) & 15);
        uint4 val = *(const uint4*)&tile[row][pch * 8];
        *(uint4*)((char*)xT + (size_t)(m0 + row) * (KPAD * 2) + (size_t)(ct * 128 + ch * 8) * 2) = val;
    }
}

// ---------- kernel: local self-correlation partials ----------
__global__ __launch_bounds__(256, 2) void k1a_corr(const float* __restrict__ x,
                                                   float* __restrict__ fpart)
{
    __shared__ float slab[2][20][68];
    const int bid   = blockIdx.x;
    const int split = bid & 15;
    const int b     = (bid >> 4) & 7;
    const int rg    = bid >> 7;
    const int y0    = rg * 16;
    const int t     = threadIdx.x;
    const int tc    = t & 15, tr = t >> 4;
    const int cs    = tc * 4;

    if (t < 160) {
        int buf = t / 80, rem = t % 80;
        int r = rem >> 2, cc = rem & 3;
        slab[buf][r][(cc < 2) ? cc : (64 + cc)] = 0.f;
    }

    float acc[25][4];
    #pragma unroll
    for (int s = 0; s < 25; ++s)
        #pragma unroll
        for (int p = 0; p < 4; ++p) acc[s][p] = 0.f;

    const float* xb = x + ((size_t)b * 1024 + split * 64) * 4096;

    const int r0 = t >> 4,         c40 = t & 15;
    const int y0r0 = y0 - 2 + r0;
    const int r1 = (t + 256) >> 4, c41 = t & 15;          // t<64 only
    const int y0r1 = y0 - 2 + r1;
    const bool has1 = (t < 64);

    #define K1A_LOAD(ch, VA, VB)                                                \
        {                                                                        \
            const float* s_ = xb + (size_t)(ch) * 4096;                          \
            VA = (y0r0 >= 0 && y0r0 < 64) ? *(const float4*)(s_ + y0r0 * 64 + c40 * 4) \
                                          : make_float4(0.f, 0.f, 0.f, 0.f);     \
            if (has1)                                                            \
                VB = (y0r1 >= 0 && y0r1 < 64) ? *(const float4*)(s_ + y0r1 * 64 + c41 * 4) \
                                              : make_float4(0.f, 0.f, 0.f, 0.f); \
        }
    #define K1A_WRITE(buf, VA, VB)                                               \
        {                                                                        \
            float2* d0 = (float2*)&slab[buf][r0][2 + c40 * 4];                   \
            d0[0] = make_float2(VA.x, VA.y);                                     \
            d0[1] = make_float2(VA.z, VA.w);                                     \
            if (has1) {                                                          \
                float2* d1 = (float2*)&slab[buf][r1][2 + c41 * 4];               \
                d1[0] = make_float2(VB.x, VB.y);                                 \
                d1[1] = make_float2(VB.z, VB.w);                                 \
            }                                                                    \
        }
    #define K1A_COMPUTE(buf)                                                     \
        {                                                                        \
            const float* base = &slab[buf][tr][cs];                              \
            float ctr[4], wf[8];                                                 \
            {                                                                    \
                const float4* pr = (const float4*)(base + 2 * 68);               \
                float4 a = pr[0], b4 = pr[1];                                    \
                wf[0]=a.x; wf[1]=a.y; wf[2]=a.z; wf[3]=a.w;                      \
                wf[4]=b4.x; wf[5]=b4.y; wf[6]=b4.z; wf[7]=b4.w;                  \
                ctr[0]=wf[2]; ctr[1]=wf[3]; ctr[2]=wf[4]; ctr[3]=wf[5];          \
                _Pragma("unroll")                                                \
                for (int dx = -2; dx <= 2; ++dx)                                 \
                    _Pragma("unroll")                                            \
                    for (int p = 0; p < 4; ++p)                                  \
                        acc[10 + dx + 2][p] += wf[p + 2 + dx] * ctr[p];          \
            }                                                                    \
            _Pragma("unroll")                                                    \
            for (int r = 0; r < 5; ++r) {                                        \
                if (r == 2) continue;                                            \
                const float4* pr = (const float4*)(base + r * 68);               \
                float4 a = pr[0], b4 = pr[1];                                    \
                wf[0]=a.x; wf[1]=a.y; wf[2]=a.z; wf[3]=a.w;                      \
                wf[4]=b4.x; wf[5]=b4.y; wf[6]=b4.z; wf[7]=b4.w;                  \
                _Pragma("unroll")                                                \
                for (int dx = -2; dx <= 2; ++dx)                                 \
                    _Pragma("unroll")                                            \
                    for (int p = 0; p < 4; ++p)                                  \
                        acc[r * 5 + dx + 2][p] += wf[p + 2 + dx] * ctr[p];       \
            }                                                                    \
        }

    float4 Sa0, Sa1, Sb0, Sb1;
    K1A_LOAD(0, Sa0, Sa1)
    K1A_LOAD(1, Sb0, Sb1)
    K1A_WRITE(0, Sa0, Sa1)
    K1A_LOAD(2, Sa0, Sa1)
    __syncthreads();

    for (int i = 0; i < 64; i += 2) {
        K1A_WRITE(1, Sb0, Sb1)
        K1A_LOAD(min(i + 3, 63), Sb0, Sb1)
        K1A_COMPUTE(0)
        __syncthreads();
        K1A_WRITE(0, Sa0, Sa1)
        K1A_LOAD(min(i + 4, 63), Sa0, Sa1)
        K1A_COMPUTE(1)
        __syncthreads();
    }
    #undef K1A_LOAD
    #undef K1A_WRITE
    #undef K1A_COMPUTE

    const int mbase = b * 4096 + (y0 + tr) * 64 + cs;
    #pragma unroll
    for (int s = 0; s < 25; ++s) {
        *(float4*)(fpart + (size_t)(split * 25 + s) * 32768 + mbase) =
            make_float4(acc[s][0], acc[s][1], acc[s][2], acc[s][3]);
    }
}

// ---------- kernel: reduce 16 partials, L2-normalize, write bf16 into xT[m][1024..1088) ----------
__global__ void k1b_norm(const float* __restrict__ fpart, unsigned short* __restrict__ xT)
{
    const int m = blockIdx.x * 256 + threadIdx.x;
    float f[25];
    #pragma unroll
    for (int s = 0; s < 25; ++s) {
        float v = 0.f;
        #pragma unroll
        for (int sp = 0; sp < 16; ++sp)
            v += fpart[(size_t)(sp * 25 + s) * 32768 + m];
        f[s] = v;
    }
    float ss = 1e-6f;
    #pragma unroll
    for (int s = 0; s < 25; ++s) ss += f[s] * f[s];
    const float inv = 1.f / sqrtf(ss);

    unsigned int w[16];
    #pragma unroll
    for (int q = 0; q < 16; ++q) w[q] = 0u;
    #pragma unroll
    for (int s = 0; s < 25; ++s) {
        unsigned int h = f2bf(f[s] * inv);
        w[s >> 1] |= h << ((s & 1) * 16);
    }
    uint4* dst = (uint4*)((char*)xT + (size_t)m * (KPAD * 2) + 2048);
    dst[0] = make_uint4(w[0],  w[1],  w[2],  w[3]);
    dst[1] = make_uint4(w[4],  w[5],  w[6],  w[7]);
    dst[2] = make_uint4(w[8],  w[9],  w[10], w[11]);
    dst[3] = make_uint4(w[12], w[13], w[14], w[15]);
    uint4 z = make_uint4(0u, 0u, 0u, 0u);
    dst[4] = z; dst[5] = z; dst[6] = z; dst[7] = z;
}

// ---------- kernel: 256x256 GEMM — ABLATION TEMPLATE ----------
// V=0: full round-6 kernel (correct; launched LAST so d_out is right).
// V=1: staging+vmcnt+barriers+MFMA, NO in-loop ds_read  -> isolates LDS-read cost.
// V=2: ds_read+barriers+MFMA, NO staging/vmcnt (stale LDS, junk out) -> isolates staging cost.
// V=3: barriers+MFMA skeleton only -> structural floor.
template<int V>
__global__ __launch_bounds__(512, 2) void kgemm_t(const unsigned short* __restrict__ xT,
                                                  const unsigned short* __restrict__ Wb,
                                                  const float* __restrict__ bias,
                                                  float* __restrict__ out)
{
    constexpr bool DO_STAGE = (V == 0 || V == 1);
    constexpr bool DO_DSRD  = (V == 0 || V == 2);

    __shared__ unsigned short LA[2][256][64];   // 64KB
    __shared__ unsigned short LB[2][256][64];   // 64KB

    const int bid = blockIdx.x;                 // 512 blocks
    const int wg  = (bid & 7) * 64 + (bid >> 3);
    const int mt  = wg >> 2, nt = wg & 3;
    const int m0  = mt * 256, n0 = nt * 256;
    const int t   = threadIdx.x;
    const int l   = t & 63, w = t >> 6;
    const int lr  = l & 15, kq = l >> 4;
    const int wm  = w >> 2, wn = w & 3;

    const int sr = l >> 3;
    const int sp = (l & 7) ^ sr;
    const unsigned short* gA = xT + (size_t)(m0 + w * 8 + sr) * KPAD + sp * 8;
    const unsigned short* gB = Wb + (size_t)(n0 + w * 8 + sr) * KPAD + sp * 8;

    // half: 0 = A rows[0:128), 1 = A[128:256), 2 = B[0:128), 3 = B[128:256)
    auto STAGE = [&](int tt, int half) {
        if constexpr (!DO_STAGE) return;
        if ((unsigned)tt >= NT) return;
        const int db = tt & 1;
        const size_t ko = (size_t)tt * 64;
        if (half < 2) {
            const unsigned short* g = gA + (size_t)(half * 128) * KPAD + ko;
            __builtin_amdgcn_global_load_lds((const void*)g,
                (void*)&LA[db][half * 128 + w * 8][0], 16, 0, 0);
            __builtin_amdgcn_global_load_lds((const void*)(g + (size_t)64 * KPAD),
                (void*)&LA[db][half * 128 + 64 + w * 8][0], 16, 0, 0);
        } else {
            const int hb = half - 2;
            const unsigned short* g = gB + (size_t)(hb * 128) * KPAD + ko;
            __builtin_amdgcn_global_load_lds((const void*)g,
                (void*)&LB[db][hb * 128 + w * 8][0], 16, 0, 0);
            __builtin_amdgcn_global_load_lds((const void*)(g + (size_t)64 * KPAD),
                (void*)&LB[db][hb * 128 + 64 + w * 8][0], 16, 0, 0);
        }
    };

    f32x4 zero = {0.f, 0.f, 0.f, 0.f};
    f32x4 acc[8][4];
    #pragma unroll
    for (int i = 0; i < 8; ++i)
        #pragma unroll
        for (int j = 0; j < 4; ++j) acc[i][j] = zero;

    bf16x8 a0[4][2], a1[4][2], b0[2][2], b1[2][2];

    #define LDA(dst, dbuf, ih)                                                   \
        _Pragma("unroll")                                                        \
        for (int i = 0; i < 4; ++i) {                                            \
            _Pragma("unroll")                                                    \
            for (int ks = 0; ks < 2; ++ks) {                                     \
                const int row = wm * 128 + ((ih) * 4 + i) * 16 + lr;             \
                const int slot = (ks * 4 + kq) ^ (row & 7);                      \
                dst[i][ks] = *(const bf16x8*)&LA[dbuf][row][slot * 8];           \
            }                                                                    \
        }
    #define LDB(dst, dbuf, jh)                                                   \
        _Pragma("unroll")                                                        \
        for (int j = 0; j < 2; ++j) {                                            \
            _Pragma("unroll")                                                    \
            for (int ks = 0; ks < 2; ++ks) {                                     \
                const int row = wn * 64 + ((jh) * 2 + j) * 16 + lr;              \
                const int slot = (ks * 4 + kq) ^ (row & 7);                      \
                dst[j][ks] = *(const bf16x8*)&LB[dbuf][row][slot * 8];           \
            }                                                                    \
        }
    #define MM(A, B, i0, j0)                                                     \
        _Pragma("unroll")                                                        \
        for (int ks = 0; ks < 2; ++ks) {                                         \
            _Pragma("unroll")                                                    \
            for (int i = 0; i < 4; ++i) {                                        \
                _Pragma("unroll")                                                \
                for (int j = 0; j < 2; ++j)                                      \
                    acc[(i0) + i][(j0) + j] = __builtin_amdgcn_mfma_f32_16x16x32_bf16( \
                        A[i][ks], B[j][ks], acc[(i0) + i][(j0) + j], 0, 0, 0);   \
            }                                                                    \
        }
    #define BAR()   asm volatile("s_barrier" ::: "memory");
    #define LGKM0() asm volatile("s_waitcnt lgkmcnt(0)" ::: "memory");           \
                    __builtin_amdgcn_sched_barrier(0);

    // prologue: stage tiles 0 and 1 fully (16 loads); vmcnt(8) drains tile 0.
    STAGE(0, 0); STAGE(0, 1); STAGE(0, 2); STAGE(0, 3);
    STAGE(1, 0); STAGE(1, 1); STAGE(1, 2); STAGE(1, 3);
    if constexpr (DO_STAGE) {
        asm volatile("s_waitcnt vmcnt(8)" ::: "memory");
    }
    BAR()

    if constexpr (!DO_DSRD) {
        // one-time fragment fill so in-loop MFMAs have defined, live operands
        LDA(a0, 0, 0)
        LDB(b0, 0, 0)
        LDA(a1, 0, 1)
        LDB(b1, 0, 1)
        LGKM0()
    }

    for (int tt = 0; tt < NT; ++tt) {
        const int db = tt & 1;
        // ---- ph1: read a0,b0; MM(a0,b0)
        if constexpr (DO_DSRD) { LDA(a0, db, 0) LDB(b0, db, 0) }
        BAR()
        LGKM0()
        __builtin_amdgcn_s_setprio(1);
        MM(a0, b0, 0, 0)
        __builtin_amdgcn_s_setprio(0);
        BAR()
        // ---- ph2: read a1,b1; MM(a0,b1)
        if constexpr (DO_DSRD) { LDA(a1, db, 1) LDB(b1, db, 1) }
        BAR()
        LGKM0()
        __builtin_amdgcn_s_setprio(1);
        MM(a0, b1, 0, 2)
        __builtin_amdgcn_s_setprio(0);
        BAR()
        // ---- ph3: stage B-lo+B-hi(t+2); MM(a1,b0)
        STAGE(tt + 2, 2);
        STAGE(tt + 2, 3);
        BAR()
        LGKM0()
        __builtin_amdgcn_s_setprio(1);
        MM(a1, b0, 4, 0)
        __builtin_amdgcn_s_setprio(0);
        BAR()
        // ---- ph4: stage A-lo+A-hi(t+2); MM(a1,b1); drain tile t+1's 8 loads
        STAGE(tt + 2, 0);
        STAGE(tt + 2, 1);
        BAR()
        LGKM0()
        __builtin_amdgcn_s_setprio(1);
        MM(a1, b1, 4, 2)
        __builtin_amdgcn_s_setprio(0);
        if constexpr (DO_STAGE) {
            if (tt + 2 < NT) {
                asm volatile("s_waitcnt vmcnt(8)" ::: "memory");
            } else {
                asm volatile("s_waitcnt vmcnt(0)" ::: "memory");
            }
        }
        BAR()
    }

    // epilogue: D col = lane&15 (n), row = (lane>>4)*4 + reg (m)
    const int bb = m0 >> 12;
    const int ms = (m0 & 4095) + wm * 128 + kq * 4;
    #pragma unroll
    for (int j = 0; j < 4; ++j) {
        const int n = n0 + wn * 64 + j * 16 + lr;
        const float bv = bias[n];
        float* ob = out + (size_t)bb * 4194304 + (size_t)n * 4096 + ms;
        #pragma unroll
        for (int i = 0; i < 8; ++i) {
            f32x4 v = acc[i][j];
            float4 o = make_float4(fmaxf(v[0] + bv, 0.f), fmaxf(v[1] + bv, 0.f),
                                   fmaxf(v[2] + bv, 0.f), fmaxf(v[3] + bv, 0.f));
            *(float4*)(ob + i * 16) = o;
        }
    }
    #undef LDA
    #undef LDB
    #undef MM
    #undef BAR
    #undef LGKM0
}

// ---------- launch ----------
extern "C" void kernel_launch(void* const* d_in, const int* in_sizes, int n_in,
                              void* d_out, int out_size, void* d_ws, size_t ws_size,
                              hipStream_t stream)
{
    const float* x    = (const float*)d_in[0];
    const float* W    = (const float*)d_in[1];
    const float* bias = (const float*)d_in[2];
    float* out        = (float*)d_out;

    char* ws = (char*)d_ws;
    // ws: xT 71,303,168 B ; Wb 2,228,224 B (total 73.5MB); fpart in d_out scratch.
    unsigned short* xT = (unsigned short*)ws;
    unsigned short* Wb = (unsigned short*)(ws + 71303168);
    float* fpart       = (float*)d_out;

    kWb_conv<<<1024, 256, 0, stream>>>(W, Wb);
    kT_conv <<<4096, 256, 0, stream>>>(x, xT);
    k1a_corr<<<512,  256, 0, stream>>>(x, fpart);
    k1b_norm<<<128,  256, 0, stream>>>(fpart, xT);

    // ---- ablation dispatches (junk/partial outputs, all overwritten by final V0) ----
    kgemm_t<1><<<512, 512, 0, stream>>>(xT, Wb, bias, out);  // no ds_read
    kgemm_t<2><<<512, 512, 0, stream>>>(xT, Wb, bias, out);  // no staging/vmcnt
    kgemm_t<3><<<512, 512, 0, stream>>>(xT, Wb, bias, out);  // skeleton
    // ---- the real, correct GEMM (must be LAST) ----
    kgemm_t<0><<<512, 512, 0, stream>>>(xT, Wb, bias, out);
}

// Round 8
// 203.483 us; speedup vs baseline: 2.0272x; 2.0272x over previous
//
#include <hip/hip_runtime.h>

// ---------- types ----------
typedef __attribute__((ext_vector_type(8))) short bf16x8;   // 8 bf16 (4 VGPRs)
typedef __attribute__((ext_vector_type(4))) float f32x4;

__device__ __forceinline__ unsigned short f2bf(float f) {
    unsigned int u = __float_as_uint(f);
    unsigned int r = (u + 0x7fffu + ((u >> 16) & 1u)) >> 16;   // RNE
    return (unsigned short)r;
}

// x: (8,1024,64,64) f32; W: (1024,1049) f32; b: (1024,); out: (8,1024,64,64) f32
// M = 32768, K = 1049 -> pad 1088 (17 K-tiles of 64), N = 1024
#define KPAD 1088
#define NT   17

// ---------- kernel: W (1024,1049) f32 -> Wb[n][k] bf16, k padded to 1088 ----------
__global__ void kWb_conv(const float* __restrict__ W, unsigned short* __restrict__ Wb)
{
    const int o = blockIdx.x;
    for (int k = threadIdx.x; k < KPAD; k += 256) {
        float v = (k < 1049) ? W[(size_t)o * 1049 + k] : 0.f;
        Wb[(size_t)o * KPAD + k] = f2bf(v);
    }
}

// ---------- kernel: transpose+convert x -> xT[m][k] bf16 (k<1024 region) ----------
__global__ __launch_bounds__(256) void kT_conv(const float* __restrict__ x,
                                               unsigned short* __restrict__ xT)
{
    __shared__ unsigned short tile[64][128];
    const int bid = blockIdx.x;          // 4096 = 512 mtiles * 8 ctiles
    const int mst = bid >> 3;
    const int ct  = bid & 7;
    const int m0  = mst * 64;
    const int b   = m0 >> 12, ms0 = m0 & 4095;
    const int t   = threadIdx.x;
    const int msq = (t & 15) * 4;
    const int cg  = t >> 4;
    const int c0  = ct * 128 + cg * 8;

    const float* src = x + ((size_t)b * 1024 + c0) * 4096 + ms0 + msq;
    float4 v[8];
    #pragma unroll
    for (int j = 0; j < 8; ++j)
        v[j] = *(const float4*)(src + (size_t)j * 4096);

    #pragma unroll
    for (int p = 0; p < 4; ++p) {
        unsigned int w[4];
        #pragma unroll
        for (int q = 0; q < 4; ++q) {
            float lo = ((const float*)&v[2 * q])[p];
            float hi = ((const float*)&v[2 * q + 1])[p];
            w[q] = (unsigned int)f2bf(lo) | ((unsigned int)f2bf(hi) << 16);
        }
        const int row = msq + p;
        const int pch = cg ^ ((row >> 2) & 15);
        *(uint4*)&tile[row][pch * 8] = make_uint4(w[0], w[1], w[2], w[3]);
    }
    __syncthreads();

    #pragma unroll
    for (int q = 0; q < 4; ++q) {
        const int flat = q * 256 + t;
        const int row  = flat >> 4, ch = flat & 15;
        const int pch  = ch ^ ((row >> 2) & 15);
        uint4 val = *(const uint4*)&tile[row][pch * 8];
        *(uint4*)((char*)xT + (size_t)(m0 + row) * (KPAD * 2) + (size_t)(ct * 128 + ch * 8) * 2) = val;
    }
}

// ---------- kernel: local self-correlation partials ----------
__global__ __launch_bounds__(256, 2) void k1a_corr(const float* __restrict__ x,
                                                   float* __restrict__ fpart)
{
    __shared__ float slab[2][20][68];
    const int bid   = blockIdx.x;
    const int split = bid & 15;
    const int b     = (bid >> 4) & 7;
    const int rg    = bid >> 7;
    const int y0    = rg * 16;
    const int t     = threadIdx.x;
    const int tc    = t & 15, tr = t >> 4;
    const int cs    = tc * 4;

    if (t < 160) {
        int buf = t / 80, rem = t % 80;
        int r = rem >> 2, cc = rem & 3;
        slab[buf][r][(cc < 2) ? cc : (64 + cc)] = 0.f;
    }

    float acc[25][4];
    #pragma unroll
    for (int s = 0; s < 25; ++s)
        #pragma unroll
        for (int p = 0; p < 4; ++p) acc[s][p] = 0.f;

    const float* xb = x + ((size_t)b * 1024 + split * 64) * 4096;

    const int r0 = t >> 4,         c40 = t & 15;
    const int y0r0 = y0 - 2 + r0;
    const int r1 = (t + 256) >> 4, c41 = t & 15;          // t<64 only
    const int y0r1 = y0 - 2 + r1;
    const bool has1 = (t < 64);

    #define K1A_LOAD(ch, VA, VB)                                                \
        {                                                                        \
            const float* s_ = xb + (size_t)(ch) * 4096;                          \
            VA = (y0r0 >= 0 && y0r0 < 64) ? *(const float4*)(s_ + y0r0 * 64 + c40 * 4) \
                                          : make_float4(0.f, 0.f, 0.f, 0.f);     \
            if (has1)                                                            \
                VB = (y0r1 >= 0 && y0r1 < 64) ? *(const float4*)(s_ + y0r1 * 64 + c41 * 4) \
                                              : make_float4(0.f, 0.f, 0.f, 0.f); \
        }
    #define K1A_WRITE(buf, VA, VB)                                               \
        {                                                                        \
            float2* d0 = (float2*)&slab[buf][r0][2 + c40 * 4];                   \
            d0[0] = make_float2(VA.x, VA.y);                                     \
            d0[1] = make_float2(VA.z, VA.w);                                     \
            if (has1) {                                                          \
                float2* d1 = (float2*)&slab[buf][r1][2 + c41 * 4];               \
                d1[0] = make_float2(VB.x, VB.y);                                 \
                d1[1] = make_float2(VB.z, VB.w);                                 \
            }                                                                    \
        }
    #define K1A_COMPUTE(buf)                                                     \
        {                                                                        \
            const float* base = &slab[buf][tr][cs];                              \
            float ctr[4], wf[8];                                                 \
            {                                                                    \
                const float4* pr = (const float4*)(base + 2 * 68);               \
                float4 a = pr[0], b4 = pr[1];                                    \
                wf[0]=a.x; wf[1]=a.y; wf[2]=a.z; wf[3]=a.w;                      \
                wf[4]=b4.x; wf[5]=b4.y; wf[6]=b4.z; wf[7]=b4.w;                  \
                ctr[0]=wf[2]; ctr[1]=wf[3]; ctr[2]=wf[4]; ctr[3]=wf[5];          \
                _Pragma("unroll")                                                \
                for (int dx = -2; dx <= 2; ++dx)                                 \
                    _Pragma("unroll")                                            \
                    for (int p = 0; p < 4; ++p)                                  \
                        acc[10 + dx + 2][p] += wf[p + 2 + dx] * ctr[p];          \
            }                                                                    \
            _Pragma("unroll")                                                    \
            for (int r = 0; r < 5; ++r) {                                        \
                if (r == 2) continue;                                            \
                const float4* pr = (const float4*)(base + r * 68);               \
                float4 a = pr[0], b4 = pr[1];                                    \
                wf[0]=a.x; wf[1]=a.y; wf[2]=a.z; wf[3]=a.w;                      \
                wf[4]=b4.x; wf[5]=b4.y; wf[6]=b4.z; wf[7]=b4.w;                  \
                _Pragma("unroll")                                                \
                for (int dx = -2; dx <= 2; ++dx)                                 \
                    _Pragma("unroll")                                            \
                    for (int p = 0; p < 4; ++p)                                  \
                        acc[r * 5 + dx + 2][p] += wf[p + 2 + dx] * ctr[p];       \
            }                                                                    \
        }

    float4 Sa0, Sa1, Sb0, Sb1;
    K1A_LOAD(0, Sa0, Sa1)
    K1A_LOAD(1, Sb0, Sb1)
    K1A_WRITE(0, Sa0, Sa1)
    K1A_LOAD(2, Sa0, Sa1)
    __syncthreads();

    for (int i = 0; i < 64; i += 2) {
        K1A_WRITE(1, Sb0, Sb1)
        K1A_LOAD(min(i + 3, 63), Sb0, Sb1)
        K1A_COMPUTE(0)
        __syncthreads();
        K1A_WRITE(0, Sa0, Sa1)
        K1A_LOAD(min(i + 4, 63), Sa0, Sa1)
        K1A_COMPUTE(1)
        __syncthreads();
    }
    #undef K1A_LOAD
    #undef K1A_WRITE
    #undef K1A_COMPUTE

    const int mbase = b * 4096 + (y0 + tr) * 64 + cs;
    #pragma unroll
    for (int s = 0; s < 25; ++s) {
        *(float4*)(fpart + (size_t)(split * 25 + s) * 32768 + mbase) =
            make_float4(acc[s][0], acc[s][1], acc[s][2], acc[s][3]);
    }
}

// ---------- kernel: reduce 16 partials, L2-normalize, write bf16 into xT[m][1024..1088) ----------
__global__ void k1b_norm(const float* __restrict__ fpart, unsigned short* __restrict__ xT)
{
    const int m = blockIdx.x * 256 + threadIdx.x;
    float f[25];
    #pragma unroll
    for (int s = 0; s < 25; ++s) {
        float v = 0.f;
        #pragma unroll
        for (int sp = 0; sp < 16; ++sp)
            v += fpart[(size_t)(sp * 25 + s) * 32768 + m];
        f[s] = v;
    }
    float ss = 1e-6f;
    #pragma unroll
    for (int s = 0; s < 25; ++s) ss += f[s] * f[s];
    const float inv = 1.f / sqrtf(ss);

    unsigned int w[16];
    #pragma unroll
    for (int q = 0; q < 16; ++q) w[q] = 0u;
    #pragma unroll
    for (int s = 0; s < 25; ++s) {
        unsigned int h = f2bf(f[s] * inv);
        w[s >> 1] |= h << ((s & 1) * 16);
    }
    uint4* dst = (uint4*)((char*)xT + (size_t)m * (KPAD * 2) + 2048);
    dst[0] = make_uint4(w[0],  w[1],  w[2],  w[3]);
    dst[1] = make_uint4(w[4],  w[5],  w[6],  w[7]);
    dst[2] = make_uint4(w[8],  w[9],  w[10], w[11]);
    dst[3] = make_uint4(w[12], w[13], w[14], w[15]);
    uint4 z = make_uint4(0u, 0u, 0u, 0u);
    dst[4] = z; dst[5] = z; dst[6] = z; dst[7] = z;
}

// ---------- kernel: 256x256 8-phase GEMM, m201-faithful scheduling ----------
// Changes vs round-6 (same geometry, same proven region timing):
//  * __builtin_amdgcn_s_barrier() instead of asm s_barrier ::: "memory"
//    (removes 8 compiler memory-fences per tile -> lets compiler overlap
//    address calc / ds_read issue with MFMA across barriers; m141 lesson).
//  * uniform staging: 1 half-tile per phase (ph1:Ahi(t+1), ph2:Bhi(t+1),
//    ph3:Alo(t+2), ph4:Blo(t+2)) instead of 0,0,4,4 (m196: coarse split hurts).
//    Race audit: every region's last ds_read is ph2-close; ph3/ph4 stages hit
//    the CURRENT buf only after that; ph1/ph2 stages hit the other buf (last
//    read 3+ barriers ago).
//  * one vmcnt(4) per tile draining exactly tile t+1 (staged 2-5 phases
//    = 1200-3000 cyc earlier >> 900 cyc HBM); tail tiles drop to vmcnt(0).
//  * K-loop unrolled x2: double-buffer index is compile-time (rule #20).
//  * lgkmcnt(0)+sched_barrier(0) only on read-phases (rule #18); lgkmcnt(8)
//    pre-barrier hint on the 12-read phases (m201).
__global__ __launch_bounds__(512, 2) void kgemm(const unsigned short* __restrict__ xT,
                                                const unsigned short* __restrict__ Wb,
                                                const float* __restrict__ bias,
                                                float* __restrict__ out)
{
    __shared__ unsigned short LA[2][256][64];   // 64KB
    __shared__ unsigned short LB[2][256][64];   // 64KB

    const int bid = blockIdx.x;                 // 512 blocks
    const int wg  = (bid & 7) * 64 + (bid >> 3);
    const int mt  = wg >> 2, nt = wg & 3;
    const int m0  = mt * 256, n0 = nt * 256;
    const int t   = threadIdx.x;
    const int l   = t & 63, w = t >> 6;
    const int lr  = l & 15, kq = l >> 4;
    const int wm  = w >> 2, wn = w & 3;

    const int sr = l >> 3;
    const int sp = (l & 7) ^ sr;
    const unsigned short* gA = xT + (size_t)(m0 + w * 8 + sr) * KPAD + sp * 8;
    const unsigned short* gB = Wb + (size_t)(n0 + w * 8 + sr) * KPAD + sp * 8;

    // half: 0 = A rows[0:128), 1 = A[128:256), 2 = B[0:128), 3 = B[128:256)
    auto STAGE = [&](int tt, int half) {
        if ((unsigned)tt >= NT) return;
        const int db = tt & 1;
        const size_t ko = (size_t)tt * 64;
        if (half < 2) {
            const unsigned short* g = gA + (size_t)(half * 128) * KPAD + ko;
            __builtin_amdgcn_global_load_lds((const void*)g,
                (void*)&LA[db][half * 128 + w * 8][0], 16, 0, 0);
            __builtin_amdgcn_global_load_lds((const void*)(g + (size_t)64 * KPAD),
                (void*)&LA[db][half * 128 + 64 + w * 8][0], 16, 0, 0);
        } else {
            const int hb = half - 2;
            const unsigned short* g = gB + (size_t)(hb * 128) * KPAD + ko;
            __builtin_amdgcn_global_load_lds((const void*)g,
                (void*)&LB[db][hb * 128 + w * 8][0], 16, 0, 0);
            __builtin_amdgcn_global_load_lds((const void*)(g + (size_t)64 * KPAD),
                (void*)&LB[db][hb * 128 + 64 + w * 8][0], 16, 0, 0);
        }
    };

    f32x4 zero = {0.f, 0.f, 0.f, 0.f};
    f32x4 acc[8][4];
    #pragma unroll
    for (int i = 0; i < 8; ++i)
        #pragma unroll
        for (int j = 0; j < 4; ++j) acc[i][j] = zero;

    bf16x8 a0[4][2], a1[4][2], b0[2][2], b1[2][2];

    #define LDA(dst, DB, ih)                                                     \
        _Pragma("unroll")                                                        \
        for (int i = 0; i < 4; ++i) {                                            \
            _Pragma("unroll")                                                    \
            for (int ks = 0; ks < 2; ++ks) {                                     \
                const int row = wm * 128 + ((ih) * 4 + i) * 16 + lr;             \
                const int slot = (ks * 4 + kq) ^ (row & 7);                      \
                dst[i][ks] = *(const bf16x8*)&LA[DB][row][slot * 8];             \
            }                                                                    \
        }
    #define LDB(dst, DB, jh)                                                     \
        _Pragma("unroll")                                                        \
        for (int j = 0; j < 2; ++j) {                                            \
            _Pragma("unroll")                                                    \
            for (int ks = 0; ks < 2; ++ks) {                                     \
                const int row = wn * 64 + ((jh) * 2 + j) * 16 + lr;              \
                const int slot = (ks * 4 + kq) ^ (row & 7);                      \
                dst[j][ks] = *(const bf16x8*)&LB[DB][row][slot * 8];             \
            }                                                                    \
        }
    #define MM(A, B, i0, j0)                                                     \
        _Pragma("unroll")                                                        \
        for (int ks = 0; ks < 2; ++ks) {                                         \
            _Pragma("unroll")                                                    \
            for (int i = 0; i < 4; ++i) {                                        \
                _Pragma("unroll")                                                \
                for (int j = 0; j < 2; ++j)                                      \
                    acc[(i0) + i][(j0) + j] = __builtin_amdgcn_mfma_f32_16x16x32_bf16( \
                        A[i][ks], B[j][ks], acc[(i0) + i][(j0) + j], 0, 0, 0);   \
            }                                                                    \
        }

    #define TILE(DB, TT)                                                         \
    {                                                                            \
        const int tti = (TT);                                                    \
        /* ---- ph1: read a0,b0 (12); stage A-hi(t+1); MM(a0,b0) */              \
        LDA(a0, DB, 0)                                                           \
        LDB(b0, DB, 0)                                                           \
        STAGE(tti + 1, 1);                                                       \
        asm volatile("s_waitcnt lgkmcnt(8)" ::: "memory");                       \
        __builtin_amdgcn_s_barrier();                                            \
        asm volatile("s_waitcnt lgkmcnt(0)" ::: "memory");                       \
        __builtin_amdgcn_sched_barrier(0);                                       \
        __builtin_amdgcn_s_setprio(1);                                           \
        MM(a0, b0, 0, 0)                                                         \
        __builtin_amdgcn_s_setprio(0);                                           \
        __builtin_amdgcn_s_barrier();                                            \
        /* ---- ph2: read a1,b1 (12); stage B-hi(t+1); MM(a0,b1) */              \
        LDA(a1, DB, 1)                                                           \
        LDB(b1, DB, 1)                                                           \
        STAGE(tti + 1, 3);                                                       \
        asm volatile("s_waitcnt lgkmcnt(8)" ::: "memory");                       \
        __builtin_amdgcn_s_barrier();                                            \
        asm volatile("s_waitcnt lgkmcnt(0)" ::: "memory");                       \
        __builtin_amdgcn_sched_barrier(0);                                       \
        __builtin_amdgcn_s_setprio(1);                                           \
        MM(a0, b1, 0, 2)                                                         \
        __builtin_amdgcn_s_setprio(0);                                           \
        __builtin_amdgcn_s_barrier();                                            \
        /* ---- ph3: stage A-lo(t+2) [A-lo last read ph2-close]; MM(a1,b0) */    \
        STAGE(tti + 2, 0);                                                       \
        __builtin_amdgcn_s_barrier();                                            \
        __builtin_amdgcn_s_setprio(1);                                           \
        MM(a1, b0, 4, 0)                                                         \
        __builtin_amdgcn_s_setprio(0);                                           \
        __builtin_amdgcn_s_barrier();                                            \
        /* ---- ph4: stage B-lo(t+2); MM(a1,b1); drain tile t+1 (vmcnt 4) */     \
        STAGE(tti + 2, 2);                                                       \
        __builtin_amdgcn_s_barrier();                                            \
        __builtin_amdgcn_s_setprio(1);                                           \
        MM(a1, b1, 4, 2)                                                         \
        __builtin_amdgcn_s_setprio(0);                                           \
        if (tti + 2 < NT) {                                                      \
            asm volatile("s_waitcnt vmcnt(4)" ::: "memory");                     \
        } else {                                                                 \
            asm volatile("s_waitcnt vmcnt(0)" ::: "memory");                     \
        }                                                                        \
        __builtin_amdgcn_s_barrier();                                            \
    }

    // prologue FIFO: Alo0,Blo0,Ahi0,Bhi0,Alo1,Blo1 (12 loads); vmcnt(4)
    // drains tile 0 completely, leaves Alo1,Blo1 in flight (steady invariant).
    STAGE(0, 0); STAGE(0, 2); STAGE(0, 1); STAGE(0, 3);
    STAGE(1, 0); STAGE(1, 2);
    asm volatile("s_waitcnt vmcnt(4)" ::: "memory");
    __builtin_amdgcn_s_barrier();

    int tt = 0;
    #pragma unroll 1
    for (int it = 0; it < (NT - 1) / 2; ++it, tt += 2) {
        TILE(0, tt)
        TILE(1, tt + 1)
    }
    TILE(0, NT - 1)

    // epilogue: D col = lane&15 (n), row = (lane>>4)*4 + reg (m)
    const int bb = m0 >> 12;
    const int ms = (m0 & 4095) + wm * 128 + kq * 4;
    #pragma unroll
    for (int j = 0; j < 4; ++j) {
        const int n = n0 + wn * 64 + j * 16 + lr;
        const float bv = bias[n];
        float* ob = out + (size_t)bb * 4194304 + (size_t)n * 4096 + ms;
        #pragma unroll
        for (int i = 0; i < 8; ++i) {
            f32x4 v = acc[i][j];
            float4 o = make_float4(fmaxf(v[0] + bv, 0.f), fmaxf(v[1] + bv, 0.f),
                                   fmaxf(v[2] + bv, 0.f), fmaxf(v[3] + bv, 0.f));
            *(float4*)(ob + i * 16) = o;
        }
    }
    #undef LDA
    #undef LDB
    #undef MM
    #undef TILE
}

// ---------- launch ----------
extern "C" void kernel_launch(void* const* d_in, const int* in_sizes, int n_in,
                              void* d_out, int out_size, void* d_ws, size_t ws_size,
                              hipStream_t stream)
{
    const float* x    = (const float*)d_in[0];
    const float* W    = (const float*)d_in[1];
    const float* bias = (const float*)d_in[2];
    float* out        = (float*)d_out;

    char* ws = (char*)d_ws;
    // ws: xT 71,303,168 B ; Wb 2,228,224 B (total 73.5MB); fpart in d_out scratch
    // (kgemm overwrites all of d_out afterwards -> deterministic replays).
    unsigned short* xT = (unsigned short*)ws;
    unsigned short* Wb = (unsigned short*)(ws + 71303168);
    float* fpart       = (float*)d_out;

    kWb_conv<<<1024, 256, 0, stream>>>(W, Wb);
    kT_conv <<<4096, 256, 0, stream>>>(x, xT);
    k1a_corr<<<512,  256, 0, stream>>>(x, fpart);
    k1b_norm<<<128,  256, 0, stream>>>(fpart, xT);
    kgemm   <<<512,  512, 0, stream>>>(xT, Wb, bias, out);
}

// Round 9
// 192.378 us; speedup vs baseline: 2.1442x; 1.0577x over previous
//
#include <hip/hip_runtime.h>

// ---------- types ----------
typedef __attribute__((ext_vector_type(8))) short bf16x8;   // 8 bf16 (4 VGPRs)
typedef __attribute__((ext_vector_type(4))) float f32x4;

__device__ __forceinline__ unsigned short f2bf(float f) {
    unsigned int u = __float_as_uint(f);
    unsigned int r = (u + 0x7fffu + ((u >> 16) & 1u)) >> 16;   // RNE
    return (unsigned short)r;
}

// x: (8,1024,64,64) f32; W: (1024,1049) f32; b: (1024,); out: (8,1024,64,64) f32
// M = 32768, K = 1049 -> pad 1088 (17 K-tiles of 64), N = 1024
#define KPAD 1088
#define NT   17

// ---------- fused front-end: k1a (blocks 0..511) | kT (512..4607) | kWb (4608..5631)
// The three are mutually independent; fusing into one launch lets the HBM-bound
// transpose overlap the VALU/LDS-bound correlation on complementary pipes (m114).
// LDS: one 16KB union (kT tile 16KB; k1a slab 10.9KB), disjoint by block range.
__global__ __launch_bounds__(256, 2) void kfront(const float* __restrict__ x,
                                                 const float* __restrict__ W,
                                                 unsigned short* __restrict__ xT,
                                                 unsigned short* __restrict__ Wb,
                                                 float* __restrict__ fpart)
{
    __shared__ float4 lds_raw[1024];     // 16384 B, 16B-aligned
    const int gbid = blockIdx.x;
    const int t    = threadIdx.x;

    if (gbid < 512) {
        // ================= k1a: local self-correlation partials =================
        // split(16) * b(8) * rowgroup(4: 16 rows); 64 ch/block; T14 async staging.
        float (*slab)[20][68] = (float (*)[20][68])lds_raw;
        const int bid   = gbid;
        const int split = bid & 15;
        const int b     = (bid >> 4) & 7;
        const int rg    = bid >> 7;
        const int y0    = rg * 16;
        const int tc    = t & 15, tr = t >> 4;
        const int cs    = tc * 4;

        if (t < 160) {
            int buf = t / 80, rem = t % 80;
            int r = rem >> 2, cc = rem & 3;
            slab[buf][r][(cc < 2) ? cc : (64 + cc)] = 0.f;
        }

        float acc[25][4];
        #pragma unroll
        for (int s = 0; s < 25; ++s)
            #pragma unroll
            for (int p = 0; p < 4; ++p) acc[s][p] = 0.f;

        const float* xb = x + ((size_t)b * 1024 + split * 64) * 4096;

        const int r0 = t >> 4,         c40 = t & 15;
        const int y0r0 = y0 - 2 + r0;
        const int r1 = (t + 256) >> 4, c41 = t & 15;          // t<64 only
        const int y0r1 = y0 - 2 + r1;
        const bool has1 = (t < 64);

        #define K1A_LOAD(ch, VA, VB)                                                \
            {                                                                        \
                const float* s_ = xb + (size_t)(ch) * 4096;                          \
                VA = (y0r0 >= 0 && y0r0 < 64) ? *(const float4*)(s_ + y0r0 * 64 + c40 * 4) \
                                              : make_float4(0.f, 0.f, 0.f, 0.f);     \
                if (has1)                                                            \
                    VB = (y0r1 >= 0 && y0r1 < 64) ? *(const float4*)(s_ + y0r1 * 64 + c41 * 4) \
                                                  : make_float4(0.f, 0.f, 0.f, 0.f); \
            }
        #define K1A_WRITE(buf, VA, VB)                                               \
            {                                                                        \
                float2* d0 = (float2*)&slab[buf][r0][2 + c40 * 4];                   \
                d0[0] = make_float2(VA.x, VA.y);                                     \
                d0[1] = make_float2(VA.z, VA.w);                                     \
                if (has1) {                                                          \
                    float2* d1 = (float2*)&slab[buf][r1][2 + c41 * 4];               \
                    d1[0] = make_float2(VB.x, VB.y);                                 \
                    d1[1] = make_float2(VB.z, VB.w);                                 \
                }                                                                    \
            }
        #define K1A_COMPUTE(buf)                                                     \
            {                                                                        \
                const float* base = &slab[buf][tr][cs];                              \
                float ctr[4], wf[8];                                                 \
                {                                                                    \
                    const float4* pr = (const float4*)(base + 2 * 68);               \
                    float4 a = pr[0], b4 = pr[1];                                    \
                    wf[0]=a.x; wf[1]=a.y; wf[2]=a.z; wf[3]=a.w;                      \
                    wf[4]=b4.x; wf[5]=b4.y; wf[6]=b4.z; wf[7]=b4.w;                  \
                    ctr[0]=wf[2]; ctr[1]=wf[3]; ctr[2]=wf[4]; ctr[3]=wf[5];          \
                    _Pragma("unroll")                                                \
                    for (int dx = -2; dx <= 2; ++dx)                                 \
                        _Pragma("unroll")                                            \
                        for (int p = 0; p < 4; ++p)                                  \
                            acc[10 + dx + 2][p] += wf[p + 2 + dx] * ctr[p];          \
                }                                                                    \
                _Pragma("unroll")                                                    \
                for (int r = 0; r < 5; ++r) {                                        \
                    if (r == 2) continue;                                            \
                    const float4* pr = (const float4*)(base + r * 68);               \
                    float4 a = pr[0], b4 = pr[1];                                    \
                    wf[0]=a.x; wf[1]=a.y; wf[2]=a.z; wf[3]=a.w;                      \
                    wf[4]=b4.x; wf[5]=b4.y; wf[6]=b4.z; wf[7]=b4.w;                  \
                    _Pragma("unroll")                                                \
                    for (int dx = -2; dx <= 2; ++dx)                                 \
                        _Pragma("unroll")                                            \
                        for (int p = 0; p < 4; ++p)                                  \
                            acc[r * 5 + dx + 2][p] += wf[p + 2 + dx] * ctr[p];       \
                }                                                                    \
            }

        float4 Sa0, Sa1, Sb0, Sb1;
        K1A_LOAD(0, Sa0, Sa1)
        K1A_LOAD(1, Sb0, Sb1)
        K1A_WRITE(0, Sa0, Sa1)
        K1A_LOAD(2, Sa0, Sa1)
        __syncthreads();

        for (int i = 0; i < 64; i += 2) {
            K1A_WRITE(1, Sb0, Sb1)
            K1A_LOAD(min(i + 3, 63), Sb0, Sb1)
            K1A_COMPUTE(0)
            __syncthreads();
            K1A_WRITE(0, Sa0, Sa1)
            K1A_LOAD(min(i + 4, 63), Sa0, Sa1)
            K1A_COMPUTE(1)
            __syncthreads();
        }
        #undef K1A_LOAD
        #undef K1A_WRITE
        #undef K1A_COMPUTE

        const int mbase = b * 4096 + (y0 + tr) * 64 + cs;
        #pragma unroll
        for (int s = 0; s < 25; ++s) {
            *(float4*)(fpart + (size_t)(split * 25 + s) * 32768 + mbase) =
                make_float4(acc[s][0], acc[s][1], acc[s][2], acc[s][3]);
        }
    } else if (gbid < 4608) {
        // ================= kT: transpose+convert x -> xT[m][k] bf16 =================
        unsigned short (*tile)[128] = (unsigned short (*)[128])lds_raw;
        const int bid = gbid - 512;          // 4096 = 512 mtiles * 8 ctiles
        const int mst = bid >> 3;
        const int ct  = bid & 7;
        const int m0  = mst * 64;
        const int b   = m0 >> 12, ms0 = m0 & 4095;
        const int msq = (t & 15) * 4;
        const int cg  = t >> 4;
        const int c0  = ct * 128 + cg * 8;

        const float* src = x + ((size_t)b * 1024 + c0) * 4096 + ms0 + msq;
        float4 v[8];
        #pragma unroll
        for (int j = 0; j < 8; ++j)
            v[j] = *(const float4*)(src + (size_t)j * 4096);

        #pragma unroll
        for (int p = 0; p < 4; ++p) {
            unsigned int w[4];
            #pragma unroll
            for (int q = 0; q < 4; ++q) {
                float lo = ((const float*)&v[2 * q])[p];
                float hi = ((const float*)&v[2 * q + 1])[p];
                w[q] = (unsigned int)f2bf(lo) | ((unsigned int)f2bf(hi) << 16);
            }
            const int row = msq + p;
            const int pch = cg ^ ((row >> 2) & 15);
            *(uint4*)&tile[row][pch * 8] = make_uint4(w[0], w[1], w[2], w[3]);
        }
        __syncthreads();

        #pragma unroll
        for (int q = 0; q < 4; ++q) {
            const int flat = q * 256 + t;
            const int row  = flat >> 4, ch = flat & 15;
            const int pch  = ch ^ ((row >> 2) & 15);
            uint4 val = *(const uint4*)&tile[row][pch * 8];
            *(uint4*)((char*)xT + (size_t)(m0 + row) * (KPAD * 2) + (size_t)(ct * 128 + ch * 8) * 2) = val;
        }
    } else {
        // ================= kWb: W f32 -> Wb[n][k] bf16, k padded =================
        const int o = gbid - 4608;           // 1024 blocks
        for (int k = t; k < KPAD; k += 256) {
            float v = (k < 1049) ? W[(size_t)o * 1049 + k] : 0.f;
            Wb[(size_t)o * KPAD + k] = f2bf(v);
        }
    }
}

// ---------- kernel: reduce 16 partials, L2-normalize, write bf16 into xT[m][1024..1088) ----------
__global__ void k1b_norm(const float* __restrict__ fpart, unsigned short* __restrict__ xT)
{
    const int m = blockIdx.x * 256 + threadIdx.x;
    float f[25];
    #pragma unroll
    for (int s = 0; s < 25; ++s) {
        float v = 0.f;
        #pragma unroll
        for (int sp = 0; sp < 16; ++sp)
            v += fpart[(size_t)(sp * 25 + s) * 32768 + m];
        f[s] = v;
    }
    float ss = 1e-6f;
    #pragma unroll
    for (int s = 0; s < 25; ++s) ss += f[s] * f[s];
    const float inv = 1.f / sqrtf(ss);

    unsigned int w[16];
    #pragma unroll
    for (int q = 0; q < 16; ++q) w[q] = 0u;
    #pragma unroll
    for (int s = 0; s < 25; ++s) {
        unsigned int h = f2bf(f[s] * inv);
        w[s >> 1] |= h << ((s & 1) * 16);
    }
    uint4* dst = (uint4*)((char*)xT + (size_t)m * (KPAD * 2) + 2048);
    dst[0] = make_uint4(w[0],  w[1],  w[2],  w[3]);
    dst[1] = make_uint4(w[4],  w[5],  w[6],  w[7]);
    dst[2] = make_uint4(w[8],  w[9],  w[10], w[11]);
    dst[3] = make_uint4(w[12], w[13], w[14], w[15]);
    uint4 z = make_uint4(0u, 0u, 0u, 0u);
    dst[4] = z; dst[5] = z; dst[6] = z; dst[7] = z;
}

// ---------- kernel: 256x256 8-phase GEMM, reads spread 12/4/8/0 across phases ----------
// vs round 8 (12,12,0,0): every MFMA phase now has concurrent LDS-pipe work
// (m196: fine interleave is the lever; coarse read-bursts serialize the pipes).
// Region race audit: A-lo last ds_read ph1-close, restaged ph3 (2 barriers later);
// A-hi last read ph3-close, restaged next-tile ph1; B-lo last read ph1, restaged
// ph4; B-hi last read ph2, restaged next-tile ph2. vmcnt FIFO identical to round 8:
// steady 4 in flight, ph4 vmcnt(4) drains exactly tile t+1; tail -> vmcnt(0).
__global__ __launch_bounds__(512, 2) void kgemm(const unsigned short* __restrict__ xT,
                                                const unsigned short* __restrict__ Wb,
                                                const float* __restrict__ bias,
                                                float* __restrict__ out)
{
    __shared__ unsigned short LA[2][256][64];   // 64KB
    __shared__ unsigned short LB[2][256][64];   // 64KB

    const int bid = blockIdx.x;                 // 512 blocks
    const int wg  = (bid & 7) * 64 + (bid >> 3);
    const int mt  = wg >> 2, nt = wg & 3;
    const int m0  = mt * 256, n0 = nt * 256;
    const int t   = threadIdx.x;
    const int l   = t & 63, w = t >> 6;
    const int lr  = l & 15, kq = l >> 4;
    const int wm  = w >> 2, wn = w & 3;

    const int sr = l >> 3;
    const int sp = (l & 7) ^ sr;
    const unsigned short* gA = xT + (size_t)(m0 + w * 8 + sr) * KPAD + sp * 8;
    const unsigned short* gB = Wb + (size_t)(n0 + w * 8 + sr) * KPAD + sp * 8;

    // half: 0 = A rows[0:128), 1 = A[128:256), 2 = B[0:128), 3 = B[128:256)
    auto STAGE = [&](int tt, int half) {
        if ((unsigned)tt >= NT) return;
        const int db = tt & 1;
        const size_t ko = (size_t)tt * 64;
        if (half < 2) {
            const unsigned short* g = gA + (size_t)(half * 128) * KPAD + ko;
            __builtin_amdgcn_global_load_lds((const void*)g,
                (void*)&LA[db][half * 128 + w * 8][0], 16, 0, 0);
            __builtin_amdgcn_global_load_lds((const void*)(g + (size_t)64 * KPAD),
                (void*)&LA[db][half * 128 + 64 + w * 8][0], 16, 0, 0);
        } else {
            const int hb = half - 2;
            const unsigned short* g = gB + (size_t)(hb * 128) * KPAD + ko;
            __builtin_amdgcn_global_load_lds((const void*)g,
                (void*)&LB[db][hb * 128 + w * 8][0], 16, 0, 0);
            __builtin_amdgcn_global_load_lds((const void*)(g + (size_t)64 * KPAD),
                (void*)&LB[db][hb * 128 + 64 + w * 8][0], 16, 0, 0);
        }
    };

    f32x4 zero = {0.f, 0.f, 0.f, 0.f};
    f32x4 acc[8][4];
    #pragma unroll
    for (int i = 0; i < 8; ++i)
        #pragma unroll
        for (int j = 0; j < 4; ++j) acc[i][j] = zero;

    bf16x8 a0[4][2], a1[4][2], b0[2][2], b1[2][2];

    #define LDA(dst, DB, ih)                                                     \
        _Pragma("unroll")                                                        \
        for (int i = 0; i < 4; ++i) {                                            \
            _Pragma("unroll")                                                    \
            for (int ks = 0; ks < 2; ++ks) {                                     \
                const int row = wm * 128 + ((ih) * 4 + i) * 16 + lr;             \
                const int slot = (ks * 4 + kq) ^ (row & 7);                      \
                dst[i][ks] = *(const bf16x8*)&LA[DB][row][slot * 8];             \
            }                                                                    \
        }
    #define LDB(dst, DB, jh)                                                     \
        _Pragma("unroll")                                                        \
        for (int j = 0; j < 2; ++j) {                                            \
            _Pragma("unroll")                                                    \
            for (int ks = 0; ks < 2; ++ks) {                                     \
                const int row = wn * 64 + ((jh) * 2 + j) * 16 + lr;              \
                const int slot = (ks * 4 + kq) ^ (row & 7);                      \
                dst[j][ks] = *(const bf16x8*)&LB[DB][row][slot * 8];             \
            }                                                                    \
        }
    #define MM(A, B, i0, j0)                                                     \
        _Pragma("unroll")                                                        \
        for (int ks = 0; ks < 2; ++ks) {                                         \
            _Pragma("unroll")                                                    \
            for (int i = 0; i < 4; ++i) {                                        \
                _Pragma("unroll")                                                \
                for (int j = 0; j < 2; ++j)                                      \
                    acc[(i0) + i][(j0) + j] = __builtin_amdgcn_mfma_f32_16x16x32_bf16( \
                        A[i][ks], B[j][ks], acc[(i0) + i][(j0) + j], 0, 0, 0);   \
            }                                                                    \
        }

    #define TILE(DB, TT)                                                         \
    {                                                                            \
        const int tti = (TT);                                                    \
        /* ph1: read a0(8)+b0(4); stage A-hi(t+1); MM(a0,b0) */                  \
        LDA(a0, DB, 0)                                                           \
        LDB(b0, DB, 0)                                                           \
        STAGE(tti + 1, 1);                                                       \
        asm volatile("s_waitcnt lgkmcnt(8)" ::: "memory");                       \
        __builtin_amdgcn_s_barrier();                                            \
        asm volatile("s_waitcnt lgkmcnt(0)" ::: "memory");                       \
        __builtin_amdgcn_sched_barrier(0);                                       \
        __builtin_amdgcn_s_setprio(1);                                           \
        MM(a0, b0, 0, 0)                                                         \
        __builtin_amdgcn_s_setprio(0);                                           \
        __builtin_amdgcn_s_barrier();                                            \
        /* ph2: read b1(4); stage B-hi(t+1); MM(a0,b1) */                        \
        LDB(b1, DB, 1)                                                           \
        STAGE(tti + 1, 3);                                                       \
        __builtin_amdgcn_s_barrier();                                            \
        asm volatile("s_waitcnt lgkmcnt(0)" ::: "memory");                       \
        __builtin_amdgcn_sched_barrier(0);                                       \
        __builtin_amdgcn_s_setprio(1);                                           \
        MM(a0, b1, 0, 2)                                                         \
        __builtin_amdgcn_s_setprio(0);                                           \
        __builtin_amdgcn_s_barrier();                                            \
        /* ph3: read a1(8); stage A-lo(t+2) [A-lo last read ph1]; MM(a1,b1) */   \
        LDA(a1, DB, 1)                                                           \
        STAGE(tti + 2, 0);                                                       \
        __builtin_amdgcn_s_barrier();                                            \
        asm volatile("s_waitcnt lgkmcnt(0)" ::: "memory");                       \
        __builtin_amdgcn_sched_barrier(0);                                       \
        __builtin_amdgcn_s_setprio(1);                                           \
        MM(a1, b1, 4, 2)                                                         \
        __builtin_amdgcn_s_setprio(0);                                           \
        __builtin_amdgcn_s_barrier();                                            \
        /* ph4: stage B-lo(t+2) [B-lo last read ph1]; MM(a1,b0); drain t+1 */    \
        STAGE(tti + 2, 2);                                                       \
        __builtin_amdgcn_s_barrier();                                            \
        __builtin_amdgcn_s_setprio(1);                                           \
        MM(a1, b0, 4, 0)                                                         \
        __builtin_amdgcn_s_setprio(0);                                           \
        if (tti + 2 < NT) {                                                      \
            asm volatile("s_waitcnt vmcnt(4)" ::: "memory");                     \
        } else {                                                                 \
            asm volatile("s_waitcnt vmcnt(0)" ::: "memory");                     \
        }                                                                        \
        __builtin_amdgcn_s_barrier();                                            \
    }

    // prologue FIFO: Alo0,Blo0,Ahi0,Bhi0,Alo1,Blo1 (12 loads); vmcnt(4)
    // drains tile 0 completely, leaves Alo1,Blo1 in flight (steady invariant).
    STAGE(0, 0); STAGE(0, 2); STAGE(0, 1); STAGE(0, 3);
    STAGE(1, 0); STAGE(1, 2);
    asm volatile("s_waitcnt vmcnt(4)" ::: "memory");
    __builtin_amdgcn_s_barrier();

    int tt = 0;
    #pragma unroll 1
    for (int it = 0; it < (NT - 1) / 2; ++it, tt += 2) {
        TILE(0, tt)
        TILE(1, tt + 1)
    }
    TILE(0, NT - 1)

    // epilogue: D col = lane&15 (n), row = (lane>>4)*4 + reg (m)
    const int bb = m0 >> 12;
    const int ms = (m0 & 4095) + wm * 128 + kq * 4;
    #pragma unroll
    for (int j = 0; j < 4; ++j) {
        const int n = n0 + wn * 64 + j * 16 + lr;
        const float bv = bias[n];
        float* ob = out + (size_t)bb * 4194304 + (size_t)n * 4096 + ms;
        #pragma unroll
        for (int i = 0; i < 8; ++i) {
            f32x4 v = acc[i][j];
            float4 o = make_float4(fmaxf(v[0] + bv, 0.f), fmaxf(v[1] + bv, 0.f),
                                   fmaxf(v[2] + bv, 0.f), fmaxf(v[3] + bv, 0.f));
            *(float4*)(ob + i * 16) = o;
        }
    }
    #undef LDA
    #undef LDB
    #undef MM
    #undef TILE
}

// ---------- launch ----------
extern "C" void kernel_launch(void* const* d_in, const int* in_sizes, int n_in,
                              void* d_out, int out_size, void* d_ws, size_t ws_size,
                              hipStream_t stream)
{
    const float* x    = (const float*)d_in[0];
    const float* W    = (const float*)d_in[1];
    const float* bias = (const float*)d_in[2];
    float* out        = (float*)d_out;

    char* ws = (char*)d_ws;
    // ws: xT 71,303,168 B ; Wb 2,228,224 B (total 73.5MB); fpart (52.4MB) in d_out
    // scratch (kgemm overwrites all of d_out afterwards -> deterministic replays).
    unsigned short* xT = (unsigned short*)ws;
    unsigned short* Wb = (unsigned short*)(ws + 71303168);
    float* fpart       = (float*)d_out;

    kfront <<<5632, 256, 0, stream>>>(x, W, xT, Wb, fpart);
    k1b_norm<<<128,  256, 0, stream>>>(fpart, xT);
    kgemm  <<<512,  512, 0, stream>>>(xT, Wb, bias, out);
}